// Round 3
// baseline (635.368 us; speedup 1.0000x reference)
//
#include <hip/hip_runtime.h>

// B=1024, S=256, D=128, H1=256, H2=64.
// R3 folding: h1_pre[s,h] = bias1[b,h] + sum_d keys[s,d] * Weff_b[d,h]
//   Weff_b[d,h] = (W1b - W1c)[d,h] + q_b[d] * W1d[d,h]   (K=128 GEMM!)
//   bias1[b,h]  = b1[h] + q_b @ (W1a + W1c)
// Per-wave Weff slice (64h x 128k bf16) = 64 VGPRs, truly register-stationary.
// GEMM1 is LDS-free (A-frags straight from global); 2 barriers/tile.

typedef unsigned short u16;
typedef unsigned int u32;
typedef short bf16x8 __attribute__((ext_vector_type(8)));
typedef float f32x4 __attribute__((ext_vector_type(4)));

#define NBATCH 1024
#define SLEN 256
#define DD 128
#define NH1 256
#define NH2 64

// ws layout (bytes)
#define WS_WBCT  0         // [256h][128k] bf16 = 65536   (W1b - W1c)^T
#define WS_WDT   65536     // [256h][128k] bf16 = 65536   W1d^T
#define WS_W2T   131072    // [64o][256h]  bf16 = 32768   W2^T
#define WS_WDS   163840    // 65 f32 (Wd[64], bd)
#define WS_BIAS1 164096    // [1024][256] f32

__device__ __forceinline__ u16 f2bf_rne(float f){
  union { float f; unsigned u; } v; v.f = f;
  unsigned r = v.u + 0x7fffu + ((v.u >> 16) & 1u);
  return (u16)(r >> 16);
}
__device__ __forceinline__ u32 pack_trunc(float a, float b){
  return (__float_as_uint(a) >> 16) | (__float_as_uint(b) & 0xffff0000u);
}
__device__ __forceinline__ float b2fl(short s){
  return __uint_as_float(((u32)(u16)s) << 16);
}
__device__ __forceinline__ bf16x8 pack8(float4 a, float4 b){
  union { u32 u[4]; bf16x8 v; } o;
  o.u[0] = pack_trunc(a.x, a.y);
  o.u[1] = pack_trunc(a.z, a.w);
  o.u[2] = pack_trunc(b.x, b.y);
  o.u[3] = pack_trunc(b.z, b.w);
  return o.v;
}
__device__ __forceinline__ int swz(int byte){   // 512B-row XOR swizzle (16B grain)
  return byte ^ (((byte >> 9) & 7) << 4);
}
__device__ __forceinline__ float fsigmoid(float x){
  return __builtin_amdgcn_rcpf(1.f + __expf(-x));
}
// barrier that does NOT drain vmcnt (prefetched global loads stay in flight)
__device__ __forceinline__ void barrier_lds(){
  asm volatile("s_waitcnt lgkmcnt(0)" ::: "memory");
  __builtin_amdgcn_s_barrier();
  asm volatile("" ::: "memory");
}

// ---- prep 1: fold weights to bf16, transposed ----
__global__ void prep_weights(const float* __restrict__ W1, const float* __restrict__ W2,
                             const float* __restrict__ Wd, const float* __restrict__ bd,
                             u16* __restrict__ WbcT, u16* __restrict__ WdT,
                             u16* __restrict__ W2T, float* __restrict__ WdS){
  int n = blockIdx.x;      // h (0..255)
  int k = threadIdx.x;     // 0..255
  if (k < DD){
    WbcT[n * DD + k] = f2bf_rne(W1[(128 + k) * NH1 + n] - W1[(256 + k) * NH1 + n]);
    WdT [n * DD + k] = f2bf_rne(W1[(384 + k) * NH1 + n]);
  }
  if (n < NH2) W2T[n * 256 + k] = f2bf_rne(W2[k * NH2 + n]);
  if (n == 0 && k < NH2) WdS[k] = Wd[k];
  if (n == 0 && k == NH2) WdS[NH2] = bd[0];
}

// ---- prep 2: per-batch layer1 bias = b1 + q @ (W1a + W1c) ----
__global__ void prep_bias(const float* __restrict__ q, const float* __restrict__ W1,
                          const float* __restrict__ b1, float* __restrict__ bias1){
  __shared__ float qsh[DD];
  int b = blockIdx.x, j = threadIdx.x;
  if (j < DD) qsh[j] = q[b * DD + j];
  __syncthreads();
  float acc = b1[j];
  #pragma unroll 8
  for (int d = 0; d < DD; ++d)
    acc += qsh[d] * (W1[d * NH1 + j] + W1[(256 + d) * NH1 + j]);
  bias1[b * NH1 + j] = acc;
}

// ---- main: one block per batch, 4 waves, 64-row s-tiles ----
__global__ __launch_bounds__(256, 2)
void seqatt_main(const float* __restrict__ queries, const float* __restrict__ keys,
                 const int* __restrict__ keys_length,
                 const u16* __restrict__ WbcT, const u16* __restrict__ WdT,
                 const u16* __restrict__ W2Tg,
                 const float* __restrict__ WdS, const float* __restrict__ bias1g,
                 const float* __restrict__ b2g, float* __restrict__ out)
{
  // LDS: 0 h1[64][512B] swz (reused as red f32[256] at end); 32768 W2T swz;
  //      65536 scores f32[256]; 66560 bias1 f32[256]; 67584 b2 f32[64];
  //      67840 wd f32[66]; 68104 red4 f32[8]
  __shared__ alignas(16) char smem[68160];
  float* scores = (float*)(smem + 65536);
  float* bias1s = (float*)(smem + 66560);
  float* b2s    = (float*)(smem + 67584);
  float* wds    = (float*)(smem + 67840);
  float* red4   = (float*)(smem + 68104);

  const int b = blockIdx.x;
  const int tid = threadIdx.x;
  const int lane = tid & 63;
  const int wave = tid >> 6;
  const int l15 = lane & 15;
  const int g   = lane >> 4;

  bias1s[tid] = bias1g[b * NH1 + tid];
  if (tid < 64) b2s[tid] = b2g[tid];
  if (tid < 65) wds[tid] = WdS[tid];
  const int klen = keys_length[b];

  // stage W2T -> LDS (swizzled), once per block
  #pragma unroll
  for (int c = 0; c < 8; ++c){
    int byte = (c * 256 + tid) * 16;
    uint4 v = *reinterpret_cast<const uint4*>((const char*)W2Tg + byte);
    *reinterpret_cast<uint4*>(smem + swz(32768 + byte)) = v;
  }

  // Weff fragments: bfrag[nt][kk], wave-stationary (64 VGPRs)
  bf16x8 bfrag[4][4];
  {
    const float* qb = queries + b * DD;
    #pragma unroll
    for (int nt = 0; nt < 4; ++nt){
      int n = (wave << 6) + (nt << 4) + l15;
      #pragma unroll
      for (int kk = 0; kk < 4; ++kk){
        int k0 = (g << 3) + (kk << 5);
        bf16x8 bc = *(const bf16x8*)(WbcT + n * DD + k0);
        bf16x8 wd = *(const bf16x8*)(WdT  + n * DD + k0);
        float4 q0 = *(const float4*)(qb + k0);
        float4 q1 = *(const float4*)(qb + k0 + 4);
        float qa[8] = {q0.x, q0.y, q0.z, q0.w, q1.x, q1.y, q1.z, q1.w};
        union { u16 s[8]; bf16x8 v; } o;
        #pragma unroll
        for (int j = 0; j < 8; ++j)
          o.s[j] = f2bf_rne(fmaf(qa[j], b2fl(wd[j]), b2fl(bc[j])));
        bfrag[nt][kk] = o.v;
      }
    }
  }

  // A fragments for tile 0 (straight from global, packed to bf16)
  const float* kbb = keys + (long)b * SLEN * DD;
  bf16x8 Abf[4][4];
  #pragma unroll
  for (int mt = 0; mt < 4; ++mt)
    #pragma unroll
    for (int kk = 0; kk < 4; ++kk){
      const float* p = kbb + (mt * 16 + l15) * DD + (g << 3) + (kk << 5);
      float4 a = *(const float4*)p;
      float4 c4 = *(const float4*)(p + 4);
      Abf[mt][kk] = pack8(a, c4);
    }

  barrier_lds();   // bias1s/b2s/wds/W2T visible

  const f32x4 fz = {0.f, 0.f, 0.f, 0.f};

  for (int st = 0; st < 4; ++st){
    const int s0 = st * 64;

    // ---- GEMM1: h1_pre = keys @ Weff (per wave: M=64, N=64, K=128), LDS-free ----
    f32x4 acc[4][4];
    #pragma unroll
    for (int mt = 0; mt < 4; ++mt)
      #pragma unroll
      for (int nt = 0; nt < 4; ++nt) acc[mt][nt] = fz;
    #pragma unroll
    for (int kk = 0; kk < 4; ++kk)
      #pragma unroll
      for (int mt = 0; mt < 4; ++mt)
        #pragma unroll
        for (int nt = 0; nt < 4; ++nt)
          acc[mt][nt] = __builtin_amdgcn_mfma_f32_16x16x32_bf16(Abf[mt][kk], bfrag[nt][kk], acc[mt][nt], 0, 0, 0);

    // ---- bias + sigmoid -> h1 LDS bf16 ----
    #pragma unroll
    for (int nt = 0; nt < 4; ++nt){
      int h = (wave << 6) + (nt << 4) + l15;
      float bia = bias1s[h];
      #pragma unroll
      for (int mt = 0; mt < 4; ++mt)
        #pragma unroll
        for (int i = 0; i < 4; ++i){
          int row = (mt << 4) + (g << 2) + i;
          float hv = fsigmoid(acc[mt][nt][i] + bia);
          *(u16*)(smem + swz(row * 512 + h * 2)) = f2bf_rne(hv);
        }
    }

    // ---- prefetch next tile's keys into raw regs (in flight across barriers) ----
    float4 rawA[16], rawB[16];
    if (st < 3){
      const float* base = kbb + (s0 + 64) * DD;
      #pragma unroll
      for (int mt = 0; mt < 4; ++mt)
        #pragma unroll
        for (int kk = 0; kk < 4; ++kk){
          const float* p = base + (mt * 16 + l15) * DD + (g << 3) + (kk << 5);
          rawA[mt * 4 + kk] = *(const float4*)p;
          rawB[mt * 4 + kk] = *(const float4*)(p + 4);
        }
    }
    barrier_lds();   // h1 visible

    // ---- GEMM2: rows [16*wave, 16*wave+16), full K=256 from LDS ----
    f32x4 acc2[4];
    #pragma unroll
    for (int nt = 0; nt < 4; ++nt) acc2[nt] = fz;
    #pragma unroll
    for (int kk2 = 0; kk2 < 8; ++kk2){
      int kb2 = ((g << 3) + (kk2 << 5)) * 2;
      bf16x8 a2 = *(const bf16x8*)(smem + swz(((wave << 4) + l15) * 512 + kb2));
      #pragma unroll
      for (int nt = 0; nt < 4; ++nt){
        bf16x8 b2f = *(const bf16x8*)(smem + swz(32768 + ((nt << 4) + l15) * 512 + kb2));
        acc2[nt] = __builtin_amdgcn_mfma_f32_16x16x32_bf16(a2, b2f, acc2[nt], 0, 0, 0);
      }
    }

    // ---- sigmoid + dot(Wd) + 16-lane reduce -> scores ----
    {
      float p0 = 0.f, p1 = 0.f, p2 = 0.f, p3 = 0.f;
      #pragma unroll
      for (int nt = 0; nt < 4; ++nt){
        int o = (nt << 4) + l15;
        float b2v = b2s[o], wdv = wds[o];
        p0 += fsigmoid(acc2[nt][0] + b2v) * wdv;
        p1 += fsigmoid(acc2[nt][1] + b2v) * wdv;
        p2 += fsigmoid(acc2[nt][2] + b2v) * wdv;
        p3 += fsigmoid(acc2[nt][3] + b2v) * wdv;
      }
      #pragma unroll
      for (int off = 1; off < 16; off <<= 1){
        p0 += __shfl_xor(p0, off);
        p1 += __shfl_xor(p1, off);
        p2 += __shfl_xor(p2, off);
        p3 += __shfl_xor(p3, off);
      }
      if (l15 == 0){
        const float sc = 0.08838834764831845f;   // 1/sqrt(128)
        float bdv = wds[64];
        int sb = s0 + (wave << 4) + (g << 2);
        scores[sb + 0] = (sb + 0 < klen) ? (p0 + bdv) * sc : -1e30f;
        scores[sb + 1] = (sb + 1 < klen) ? (p1 + bdv) * sc : -1e30f;
        scores[sb + 2] = (sb + 2 < klen) ? (p2 + bdv) * sc : -1e30f;
        scores[sb + 3] = (sb + 3 < klen) ? (p3 + bdv) * sc : -1e30f;
      }
    }

    // ---- pack prefetched keys into A fragments for next tile ----
    if (st < 3){
      #pragma unroll
      for (int mt = 0; mt < 4; ++mt)
        #pragma unroll
        for (int kk = 0; kk < 4; ++kk)
          Abf[mt][kk] = pack8(rawA[mt * 4 + kk], rawB[mt * 4 + kk]);
    }
    barrier_lds();   // h1 reads + scores done before next tile overwrites
  }

  // ---- softmax over S=256 ----
  {
    float v = scores[tid];
    float m = v;
    #pragma unroll
    for (int off = 32; off >= 1; off >>= 1) m = fmaxf(m, __shfl_xor(m, off));
    if (lane == 0) red4[wave] = m;
    __syncthreads();
    float mx = fmaxf(fmaxf(red4[0], red4[1]), fmaxf(red4[2], red4[3]));
    float e = __expf(v - mx);
    float ssum = e;
    #pragma unroll
    for (int off = 32; off >= 1; off >>= 1) ssum += __shfl_xor(ssum, off);
    if (lane == 0) red4[4 + wave] = ssum;
    __syncthreads();
    float tot = red4[4] + red4[5] + red4[6] + red4[7];
    scores[tid] = e * __builtin_amdgcn_rcpf(tot);
    __syncthreads();
  }

  // ---- out[b][d] = sum_s w[s] * keys[b][s][d]  (fp32, keys mostly L2-resident) ----
  {
    float* red = (float*)smem;
    int d = tid & 127, half = tid >> 7;
    const float* kb = keys + ((long)b * SLEN + half * 128) * DD + d;
    float acc = 0.f;
    #pragma unroll 4
    for (int s2 = 0; s2 < 128; ++s2) acc += scores[half * 128 + s2] * kb[s2 * DD];
    red[tid] = acc;
    __syncthreads();
    if (tid < 128) out[b * DD + tid] = red[tid] + red[128 + tid];
  }
}

extern "C" void kernel_launch(void* const* d_in, const int* in_sizes, int n_in,
                              void* d_out, int out_size, void* d_ws, size_t ws_size,
                              hipStream_t stream) {
  const float* queries     = (const float*)d_in[0];
  const float* keys        = (const float*)d_in[1];
  const int*   keys_length = (const int*)d_in[2];
  const float* W1 = (const float*)d_in[3];
  const float* b1 = (const float*)d_in[4];
  const float* W2 = (const float*)d_in[5];
  const float* b2 = (const float*)d_in[6];
  const float* Wd = (const float*)d_in[7];
  const float* bd = (const float*)d_in[8];
  float* out = (float*)d_out;
  char* ws = (char*)d_ws;

  u16*   WbcT  = (u16*)(ws + WS_WBCT);
  u16*   WdT   = (u16*)(ws + WS_WDT);
  u16*   W2T   = (u16*)(ws + WS_W2T);
  float* WdS   = (float*)(ws + WS_WDS);
  float* bias1 = (float*)(ws + WS_BIAS1);

  prep_weights<<<dim3(256), dim3(256), 0, stream>>>(W1, W2, Wd, bd, WbcT, WdT, W2T, WdS);
  prep_bias<<<dim3(NBATCH), dim3(256), 0, stream>>>(queries, W1, b1, bias1);
  seqatt_main<<<dim3(NBATCH), dim3(256), 0, stream>>>(queries, keys, keys_length,
                                                      WbcT, WdT, W2T, WdS, bias1, b2, out);
}

// Round 4
// 105.703 us; speedup vs baseline: 6.0109x; 6.0109x over previous
//
#include <hip/hip_runtime.h>

// B=1024, S=256, D=128, H1=256, H2=64.
// h1_pre[s,h] = bias1[b,h] + sum_d keys[s,d] * Weff_b[d,h]   (K=128 GEMM)
//   Weff_b[d,h] = (W1b - W1c)[d,h] + q_b[d] * W1d[d,h]
//   bias1[b,h]  = b1[h] + q_b @ (W1a + W1c)
// R4: keys staged via global_load_lds (zero-VGPR DMA), double-buffered,
//     counted vmcnt(4) + lgkm-only barriers; Weff 64 VGPR wave-stationary;
//     GEMM2 4-way k-split with bf16 partial reduce (R1-validated layout).

typedef unsigned short u16;
typedef unsigned int u32;
typedef short bf16x8 __attribute__((ext_vector_type(8)));
typedef float f32x4 __attribute__((ext_vector_type(4)));

#define NBATCH 1024
#define SLEN 256
#define DD 128
#define NH1 256
#define NH2 64

// ws layout (bytes)
#define WS_WBCT  0         // [256h][128k] bf16  (W1b - W1c)^T
#define WS_WDT   65536     // [256h][128k] bf16  W1d^T
#define WS_W2T   131072    // [64o][256h]  bf16  W2^T
#define WS_WDS   163840    // 65 f32 (Wd[64], bd)
#define WS_WSUM  165888    // [128d][256h] f32   W1a + W1c
#define WS_BIAS1 296960    // [1024][256] f32

__device__ __forceinline__ u16 f2bf_rne(float f){
  union { float f; unsigned u; } v; v.f = f;
  unsigned r = v.u + 0x7fffu + ((v.u >> 16) & 1u);
  return (u16)(r >> 16);
}
__device__ __forceinline__ u32 pack_trunc(float a, float b){
  return (__float_as_uint(a) >> 16) | (__float_as_uint(b) & 0xffff0000u);
}
__device__ __forceinline__ float b2fl(short s){
  return __uint_as_float(((u32)(u16)s) << 16);
}
__device__ __forceinline__ bf16x8 pack8(float4 a, float4 b){
  union { u32 u[4]; bf16x8 v; } o;
  o.u[0] = pack_trunc(a.x, a.y);
  o.u[1] = pack_trunc(a.z, a.w);
  o.u[2] = pack_trunc(b.x, b.y);
  o.u[3] = pack_trunc(b.z, b.w);
  return o.v;
}
__device__ __forceinline__ int swz(int byte){   // 512B-row XOR swizzle (16B grain), involution
  return byte ^ (((byte >> 9) & 7) << 4);
}
__device__ __forceinline__ float fsigmoid(float x){
  return __builtin_amdgcn_rcpf(1.f + __expf(-x));
}
// async global->LDS, 16B per lane; lds dest must be wave-uniform (HW adds lane*16)
typedef const __attribute__((address_space(1))) unsigned gu32;
typedef __attribute__((address_space(3))) unsigned lu32;
__device__ __forceinline__ void gload16(const void* g, void* lds){
  __builtin_amdgcn_global_load_lds((gu32*)g, (lu32*)lds, 16, 0, 0);
}
__device__ __forceinline__ void barrier_lds(){
  asm volatile("s_waitcnt lgkmcnt(0)" ::: "memory");
  __builtin_amdgcn_s_barrier();
  asm volatile("" ::: "memory");
}

// ---- prep 1: fold weights to bf16, transposed; also Wsum = W1a + W1c ----
__global__ void prep_weights(const float* __restrict__ W1, const float* __restrict__ W2,
                             const float* __restrict__ Wd, const float* __restrict__ bd,
                             u16* __restrict__ WbcT, u16* __restrict__ WdT,
                             u16* __restrict__ W2T, float* __restrict__ WdS,
                             float* __restrict__ Wsum){
  int n = blockIdx.x;      // h (0..255)
  int k = threadIdx.x;     // 0..255
  if (k < DD){
    WbcT[n * DD + k] = f2bf_rne(W1[(128 + k) * NH1 + n] - W1[(256 + k) * NH1 + n]);
    WdT [n * DD + k] = f2bf_rne(W1[(384 + k) * NH1 + n]);
    Wsum[k * NH1 + n] = W1[k * NH1 + n] + W1[(256 + k) * NH1 + n];
  }
  if (n < NH2) W2T[n * 256 + k] = f2bf_rne(W2[k * NH2 + n]);
  if (n == 0 && k < NH2) WdS[k] = Wd[k];
  if (n == 0 && k == NH2) WdS[NH2] = bd[0];
}

// ---- prep 2: per-batch layer1 bias = b1 + q @ Wsum ----
__global__ void prep_bias(const float* __restrict__ q, const float* __restrict__ Wsum,
                          const float* __restrict__ b1, float* __restrict__ bias1){
  __shared__ float qsh[DD];
  int b = blockIdx.x, j = threadIdx.x;
  if (j < DD) qsh[j] = q[b * DD + j];
  __syncthreads();
  float acc = b1[j];
  #pragma unroll 8
  for (int d = 0; d < DD; ++d)
    acc += qsh[d] * Wsum[d * NH1 + j];
  bias1[b * NH1 + j] = acc;
}

// ---- main: one block per batch, 4 waves, 8 s-tiles of 32 rows ----
__global__ __launch_bounds__(256, 2)
void seqatt_main(const float* __restrict__ queries, const float* __restrict__ keys,
                 const int* __restrict__ keys_length,
                 const u16* __restrict__ WbcT, const u16* __restrict__ WdT,
                 const u16* __restrict__ W2Tg,
                 const float* __restrict__ WdS, const float* __restrict__ bias1g,
                 const float* __restrict__ b2g, float* __restrict__ out)
{
  // LDS: 0 kbuf[2][32][128]f32 swz (32K); 32768 h1[32][512B] swz (16K, reused as
  //      epilogue red); 49152 red bf16[4][32][64] (16K); 65536 scores f32[256];
  //      66560 bias1 f32[256]; 67584 b2 f32[64]; 67840 wd f32[66]; 68104 red4 f32[8]
  __shared__ alignas(16) char smem[68160];
  float* scores = (float*)(smem + 65536);
  float* bias1s = (float*)(smem + 66560);
  float* b2s    = (float*)(smem + 67584);
  float* wds    = (float*)(smem + 67840);
  float* red4   = (float*)(smem + 68104);

  const int b = blockIdx.x;
  const int tid = threadIdx.x;
  const int lane = tid & 63;
  const int wave = tid >> 6;
  const int l15 = lane & 15;
  const int g   = lane >> 4;

  bias1s[tid] = bias1g[b * NH1 + tid];
  if (tid < 64) b2s[tid] = b2g[tid];
  if (tid < 65) wds[tid] = WdS[tid];
  const int klen = keys_length[b];
  const float* kbb = keys + (long)b * SLEN * DD;

  // Weff fragments: bfrag[nt][kk], wave-stationary (64 VGPRs)
  bf16x8 bfrag[4][4];
  {
    const float* qb = queries + b * DD;
    #pragma unroll
    for (int nt = 0; nt < 4; ++nt){
      int n = (wave << 6) + (nt << 4) + l15;
      #pragma unroll
      for (int kk = 0; kk < 4; ++kk){
        int k0 = (g << 3) + (kk << 5);
        bf16x8 bc = *(const bf16x8*)(WbcT + n * DD + k0);
        bf16x8 wd = *(const bf16x8*)(WdT  + n * DD + k0);
        float4 q0 = *(const float4*)(qb + k0);
        float4 q1 = *(const float4*)(qb + k0 + 4);
        float qa[8] = {q0.x, q0.y, q0.z, q0.w, q1.x, q1.y, q1.z, q1.w};
        union { u16 s[8]; bf16x8 v; } o;
        #pragma unroll
        for (int j = 0; j < 8; ++j)
          o.s[j] = f2bf_rne(fmaf(qa[j], b2fl(wd[j]), b2fl(bc[j])));
        bfrag[nt][kk] = o.v;
      }
    }
  }
  // W2 k-quarter fragments: w2frag[nt][kk2] (32 VGPRs), wave w owns k in [w*64, w*64+64)
  bf16x8 w2frag[4][2];
  #pragma unroll
  for (int nt = 0; nt < 4; ++nt)
    #pragma unroll
    for (int kk2 = 0; kk2 < 2; ++kk2)
      w2frag[nt][kk2] = *(const bf16x8*)(W2Tg + ((nt << 4) + l15) * 256 + (wave << 6) + (kk2 << 5) + (g << 3));

  // stage tile 0 (async DMA; global src pre-swizzled so LDS reads can use swz())
  #pragma unroll
  for (int c = 0; c < 4; ++c){
    int n = c * 256 + (wave << 6) + lane;
    int u = swz(n * 16);
    gload16(kbb + (u >> 9) * DD + ((u >> 4) & 31) * 4,
            smem + ((c * 256 + (wave << 6)) * 16));
  }
  barrier_lds();   // bias1s/b2s/wds visible (DMA still in flight)

  const f32x4 fz = {0.f, 0.f, 0.f, 0.f};

  for (int st = 0; st < 8; ++st){
    const int s0 = st * 32;
    const int kb_base = (st & 1) * 16384;

    // issue next tile's DMA, then wait for THIS tile's 4 loads (counted vmcnt)
    if (st < 7){
      const int nb = ((st + 1) & 1) * 16384;
      #pragma unroll
      for (int c = 0; c < 4; ++c){
        int n = c * 256 + (wave << 6) + lane;
        int u = swz(n * 16);
        gload16(kbb + (s0 + 32 + (u >> 9)) * DD + ((u >> 4) & 31) * 4,
                smem + (nb + (c * 256 + (wave << 6)) * 16));
      }
      asm volatile("s_waitcnt vmcnt(4) lgkmcnt(0)" ::: "memory");
    } else {
      asm volatile("s_waitcnt vmcnt(0) lgkmcnt(0)" ::: "memory");
    }
    __builtin_amdgcn_s_barrier();
    __builtin_amdgcn_sched_barrier(0);

    // ---- GEMM1: h1_pre = keys @ Weff (per wave M=32, N=64, K=128) ----
    f32x4 acc[2][4];
    #pragma unroll
    for (int mt = 0; mt < 2; ++mt)
      #pragma unroll
      for (int nt = 0; nt < 4; ++nt) acc[mt][nt] = fz;
    #pragma unroll
    for (int kk = 0; kk < 4; ++kk){
      bf16x8 af[2];
      #pragma unroll
      for (int mt = 0; mt < 2; ++mt){
        int fb = kb_base + ((mt << 4) + l15) * 512 + (kk << 7) + (g << 5);
        float4 a = *(const float4*)(smem + swz(fb));
        float4 c4 = *(const float4*)(smem + swz(fb + 16));
        af[mt] = pack8(a, c4);
      }
      #pragma unroll
      for (int mt = 0; mt < 2; ++mt)
        #pragma unroll
        for (int nt = 0; nt < 4; ++nt)
          acc[mt][nt] = __builtin_amdgcn_mfma_f32_16x16x32_bf16(af[mt], bfrag[nt][kk], acc[mt][nt], 0, 0, 0);
    }

    // ---- bias + sigmoid -> h1 LDS bf16 (swz) ----
    #pragma unroll
    for (int nt = 0; nt < 4; ++nt){
      int h = (wave << 6) + (nt << 4) + l15;
      float bia = bias1s[h];
      #pragma unroll
      for (int mt = 0; mt < 2; ++mt)
        #pragma unroll
        for (int i = 0; i < 4; ++i){
          int row = (mt << 4) + (g << 2) + i;
          float hv = fsigmoid(acc[mt][nt][i] + bia);
          *(u16*)(smem + swz(32768 + row * 512 + h * 2)) = f2bf_rne(hv);
        }
    }
    asm volatile("s_waitcnt lgkmcnt(0)" ::: "memory");
    __builtin_amdgcn_s_barrier();       // h1 visible (DMA stays in flight)
    __builtin_amdgcn_sched_barrier(0);

    // ---- GEMM2: per-wave k-quarter partial (M=32, N=64, K=64) ----
    f32x4 acc2[2][4];
    #pragma unroll
    for (int mt = 0; mt < 2; ++mt)
      #pragma unroll
      for (int nt = 0; nt < 4; ++nt) acc2[mt][nt] = fz;
    #pragma unroll
    for (int kk2 = 0; kk2 < 2; ++kk2){
      int kb = ((wave << 6) + (kk2 << 5) + (g << 3)) * 2;
      bf16x8 a2[2];
      #pragma unroll
      for (int mt = 0; mt < 2; ++mt)
        a2[mt] = *(const bf16x8*)(smem + swz(32768 + ((mt << 4) + l15) * 512 + kb));
      #pragma unroll
      for (int mt = 0; mt < 2; ++mt)
        #pragma unroll
        for (int nt = 0; nt < 4; ++nt)
          acc2[mt][nt] = __builtin_amdgcn_mfma_f32_16x16x32_bf16(a2[mt], w2frag[nt][kk2], acc2[mt][nt], 0, 0, 0);
    }
    // write bf16 partials
    {
      char* rbase = smem + 49152 + (wave << 12);
      #pragma unroll
      for (int mt = 0; mt < 2; ++mt)
        #pragma unroll
        for (int nt = 0; nt < 4; ++nt)
          #pragma unroll
          for (int i = 0; i < 4; ++i){
            int row = (mt << 4) + (g << 2) + i;
            *(u16*)(rbase + (row << 7) + (((nt << 4) + l15) << 1)) =
                (u16)(__float_as_uint(acc2[mt][nt][i]) >> 16);
          }
    }
    asm volatile("s_waitcnt lgkmcnt(0)" ::: "memory");
    __builtin_amdgcn_s_barrier();       // partials visible
    __builtin_amdgcn_sched_barrier(0);

    // ---- reduce 4 partials, bias2, sigmoid, dot(Wd) -> score ----
    {
      int r = tid >> 3, og = tid & 7;
      const char* rb = smem + 49152 + (r << 7) + (og << 4);
      bf16x8 v0 = *(const bf16x8*)(rb);
      bf16x8 v1 = *(const bf16x8*)(rb + 4096);
      bf16x8 v2 = *(const bf16x8*)(rb + 8192);
      bf16x8 v3 = *(const bf16x8*)(rb + 12288);
      float p = 0.f;
      #pragma unroll
      for (int j = 0; j < 8; ++j){
        int o = (og << 3) + j;
        float s4 = (b2fl(v0[j]) + b2fl(v1[j])) + (b2fl(v2[j]) + b2fl(v3[j]));
        p += fsigmoid(s4 + b2s[o]) * wds[o];
      }
      p += __shfl_xor(p, 1);
      p += __shfl_xor(p, 2);
      p += __shfl_xor(p, 4);
      if (og == 0){
        int s = s0 + r;
        float sc = (p + wds[64]) * 0.08838834764831845f;   // 1/sqrt(128)
        scores[s] = (s < klen) ? sc : -1e30f;
      }
    }
    // no extra barrier: next iter's barrier#1/#2 order red reads before rewrites
  }

  barrier_lds();   // scores visible

  // ---- softmax over S=256 ----
  {
    float v = scores[tid];
    float m = v;
    #pragma unroll
    for (int off = 32; off >= 1; off >>= 1) m = fmaxf(m, __shfl_xor(m, off));
    if (lane == 0) red4[wave] = m;
    __syncthreads();
    float mx = fmaxf(fmaxf(red4[0], red4[1]), fmaxf(red4[2], red4[3]));
    float e = __expf(v - mx);
    float ssum = e;
    #pragma unroll
    for (int off = 32; off >= 1; off >>= 1) ssum += __shfl_xor(ssum, off);
    if (lane == 0) red4[4 + wave] = ssum;
    __syncthreads();
    float tot = red4[4] + red4[5] + red4[6] + red4[7];
    scores[tid] = e * __builtin_amdgcn_rcpf(tot);
    __syncthreads();
  }

  // ---- out[b][d] = sum_s w[s] * keys[b][s][d] (fp32; keys L2-resident) ----
  {
    float* red = (float*)(smem + 32768);
    int d = tid & 127, half = tid >> 7;
    const float* kb = keys + ((long)b * SLEN + half * 128) * DD + d;
    float acc = 0.f;
    #pragma unroll 4
    for (int s2 = 0; s2 < 128; ++s2) acc += scores[half * 128 + s2] * kb[s2 * DD];
    red[tid] = acc;
    __syncthreads();
    if (tid < 128) out[b * DD + tid] = red[tid] + red[128 + tid];
  }
}

extern "C" void kernel_launch(void* const* d_in, const int* in_sizes, int n_in,
                              void* d_out, int out_size, void* d_ws, size_t ws_size,
                              hipStream_t stream) {
  const float* queries     = (const float*)d_in[0];
  const float* keys        = (const float*)d_in[1];
  const int*   keys_length = (const int*)d_in[2];
  const float* W1 = (const float*)d_in[3];
  const float* b1 = (const float*)d_in[4];
  const float* W2 = (const float*)d_in[5];
  const float* b2 = (const float*)d_in[6];
  const float* Wd = (const float*)d_in[7];
  const float* bd = (const float*)d_in[8];
  float* out = (float*)d_out;
  char* ws = (char*)d_ws;

  u16*   WbcT  = (u16*)(ws + WS_WBCT);
  u16*   WdT   = (u16*)(ws + WS_WDT);
  u16*   W2T   = (u16*)(ws + WS_W2T);
  float* WdS   = (float*)(ws + WS_WDS);
  float* Wsum  = (float*)(ws + WS_WSUM);
  float* bias1 = (float*)(ws + WS_BIAS1);

  prep_weights<<<dim3(256), dim3(256), 0, stream>>>(W1, W2, Wd, bd, WbcT, WdT, W2T, WdS, Wsum);
  prep_bias<<<dim3(NBATCH), dim3(256), 0, stream>>>(queries, Wsum, b1, bias1);
  seqatt_main<<<dim3(NBATCH), dim3(256), 0, stream>>>(queries, keys, keys_length,
                                                      WbcT, WdT, W2T, WdS, bias1, b2, out);
}